// Round 7
// baseline (184.893 us; speedup 1.0000x reference)
//
#include <hip/hip_runtime.h>
#include <hip/hip_bf16.h>

#define NN 4096
#define IN_DIM 512
#define NH 8
#define DD 64
#define HD 512    // NH*DD
#define LOG2E 1.4426950408889634f
#define CAST_WGS 2304   // (524288+65536)/256 exactly
#define SCAN_WGS 1024

// Workspace: d1t 4MB + Ab 4MB + Wb 0.5MB + srcT/trgT 0.25MB + bm 2MB = 10.75 MB
// d1t is stored in FRAGMENT ORDER: 16B chunk index [h][jt][dt][lane] holds
// Vt[d=dt*16+(lane&15)][j = jt*32 + (lane>>4)*8 .. +8] as 8 bf16.

typedef __attribute__((ext_vector_type(8))) short short8;
typedef __attribute__((ext_vector_type(4))) float f32x4;

typedef __attribute__((address_space(1))) const unsigned int gu32;
typedef __attribute__((address_space(3))) unsigned int lu32;

static __device__ __forceinline__ unsigned short f2bf(float x) {
    __hip_bfloat16 h = __float2bfloat16(x);
    return *reinterpret_cast<unsigned short*>(&h);
}

// packed f32->bf16 RNE, 2-at-a-time (T12: verified gfx950 mnemonic, no builtin)
static __device__ __forceinline__ unsigned cvtpk_bf16(float a, float b) {
    unsigned r;
    asm("v_cvt_pk_bf16_f32 %0, %1, %2" : "=v"(r) : "v"(a), "v"(b));
    return r;
}

// async global->LDS, 16B per lane. LDS dest is wave-uniform base + lane*16
// (m104); our fragment-order layout matches exactly. Size must be literal.
static __device__ __forceinline__ void gload_lds16(const void* g, void* l) {
    __builtin_amdgcn_global_load_lds((gu32*)g, (lu32*)l, 16, 0, 0);
}

// ---------------- K0: bf16 cast of data/W + conn edge-bitmask scan -----------
// (frozen)
__global__ __launch_bounds__(256) void k_cast_scan(const float* __restrict__ inA,
                                                   unsigned short* __restrict__ outA,
                                                   int n4A,
                                                   const float* __restrict__ inB,
                                                   unsigned short* __restrict__ outB,
                                                   int n4B,
                                                   const float* __restrict__ conn,
                                                   unsigned long long* __restrict__ bm) {
    if (blockIdx.x >= CAST_WGS) {
        const int lane = threadIdx.x & 63;
        const int w = threadIdx.x >> 6;
        const int row = (blockIdx.x - CAST_WGS) * 4 + w;
        const float* crow = conn + (size_t)row * NN;
        unsigned long long keep = 0;
#pragma unroll 8
        for (int t = 0; t < 64; t++) {
            float c = crow[t * 64 + lane];                 // 256B coalesced
            unsigned long long m = __ballot(c == 0.0f);    // kept edge == 0.0f
            if (lane == t) keep = m;
        }
        bm[(size_t)row * 64 + lane] = keep;                // 512B coalesced
        return;
    }
    int t = blockIdx.x * 256 + threadIdx.x;
    const float* in;
    unsigned short* out;
    if (t < n4A) {
        in = inA; out = outA;
    } else {
        t -= n4A;
        if (t >= n4B) return;
        in = inB; out = outB;
    }
    float4 v = ((const float4*)in)[t];
    ushort4 o;
    o.x = f2bf(v.x); o.y = f2bf(v.y); o.z = f2bf(v.z); o.w = f2bf(v.w);
    ((ushort4*)out)[t] = o;
}

// ---------------- K1: split-K GEMM (bf16 MFMA) + fused src/trg projection ----
// (frozen from R6 — split-K was null but harmless; kept to isolate flash delta)
__global__ __launch_bounds__(512) void k_gemm_fused(const unsigned short* __restrict__ Ab,
                                                    const unsigned short* __restrict__ Wb,
                                                    const float* __restrict__ bias,
                                                    const float* __restrict__ sp,
                                                    const float* __restrict__ tp,
                                                    unsigned short* __restrict__ d1t,
                                                    float* __restrict__ srcT,
                                                    float* __restrict__ trgT) {
    __shared__ f32x4 cbuf[4][4 * 64];     // 16KB: [row-quad][mt*64+lane]
    const int lane = threadIdx.x & 63;
    const int w8 = threadIdx.x >> 6;      // 0..7
    const int w  = w8 & 3;                // row-quad within tile
    const int kh = w8 >> 2;               // k-half
    const int col = lane & 15;
    const int quad = lane >> 4;
    const int koff = quad * 8 + kh * 256;
    const int h = blockIdx.x;
    const int m0 = h * 64;
    const int n0 = blockIdx.y * 64;

    const short8* ap  = (const short8*)(Ab + (size_t)(n0 + w * 16 + col) * IN_DIM + koff);
    const short8* bp0 = (const short8*)(Wb + (size_t)(m0 +  0 + col) * IN_DIM + koff);
    const short8* bp1 = (const short8*)(Wb + (size_t)(m0 + 16 + col) * IN_DIM + koff);
    const short8* bp2 = (const short8*)(Wb + (size_t)(m0 + 32 + col) * IN_DIM + koff);
    const short8* bp3 = (const short8*)(Wb + (size_t)(m0 + 48 + col) * IN_DIM + koff);

    f32x4 acc0 = {0.f, 0.f, 0.f, 0.f}, acc1 = acc0, acc2 = acc0, acc3 = acc0;

#pragma unroll 8
    for (int ks = 0; ks < 8; ks++) {
        short8 a  = ap[ks * 4];
        short8 b0 = bp0[ks * 4];
        short8 b1 = bp1[ks * 4];
        short8 b2 = bp2[ks * 4];
        short8 b3 = bp3[ks * 4];
        acc0 = __builtin_amdgcn_mfma_f32_16x16x32_bf16(a, b0, acc0, 0, 0, 0);
        acc1 = __builtin_amdgcn_mfma_f32_16x16x32_bf16(a, b1, acc1, 0, 0, 0);
        acc2 = __builtin_amdgcn_mfma_f32_16x16x32_bf16(a, b2, acc2, 0, 0, 0);
        acc3 = __builtin_amdgcn_mfma_f32_16x16x32_bf16(a, b3, acc3, 0, 0, 0);
    }

    // ---- combine k-halves ----
    if (kh == 1) {
        cbuf[w][0 * 64 + lane] = acc0;
        cbuf[w][1 * 64 + lane] = acc1;
        cbuf[w][2 * 64 + lane] = acc2;
        cbuf[w][3 * 64 + lane] = acc3;
    }
    __syncthreads();
    if (kh == 1) return;
    acc0 += cbuf[w][0 * 64 + lane];
    acc1 += cbuf[w][1 * 64 + lane];
    acc2 += cbuf[w][2 * 64 + lane];
    acc3 += cbuf[w][3 * 64 + lane];

    const int rbase = n0 + w * 16 + quad * 4;
    const int jt  = (n0 >> 5) + (w >> 1);
    const int kqf = ((w & 1) << 1) + (quad >> 1);
    const int half = quad & 1;
    f32x4 accs[4] = {acc0, acc1, acc2, acc3};
    float ps[4] = {0.f, 0.f, 0.f, 0.f};
    float pt[4] = {0.f, 0.f, 0.f, 0.f};
#pragma unroll
    for (int mt = 0; mt < 4; mt++) {
        const int m = m0 + mt * 16 + col;
        const float bv  = bias[m];
        const float spv = sp[m];
        const float tpv = tp[m];
        ushort4 pack;
        unsigned short* pk = (unsigned short*)&pack;
#pragma unroll
        for (int r = 0; r < 4; r++) {
            float v = accs[mt][r] + bv;
            pk[r] = f2bf(v);
            ps[r] += v * spv;
            pt[r] += v * tpv;
        }
        size_t boff = ((((size_t)(h * 128 + jt) * 4 + mt) * 64 + kqf * 16 + col) << 4)
                    + ((size_t)half << 3);
        *(ushort4*)((char*)d1t + boff) = pack;
    }
#pragma unroll
    for (int off = 1; off <= 8; off <<= 1) {
#pragma unroll
        for (int r = 0; r < 4; r++) {
            ps[r] += __shfl_xor(ps[r], off, 64);
            pt[r] += __shfl_xor(pt[r], off, 64);
        }
    }
    if (col < 4)
        srcT[(size_t)h * NN + rbase + col] = ps[col] * LOG2E;
    else if (col < 8)
        trgT[(size_t)h * NN + rbase + col - 4] = pt[col - 4] * LOG2E;
}

// ---------------- K2: dense flash attention (v5) -----------------------------
// R6 diagnosis: ~1700cy/step stall. (a) phase-4 scalar loads issued right
// before __syncthreads' vmcnt(0) drain -> full L2 latency exposed每step;
// (b) reg-staged LDS path costs 2 ds_write + 8 VGPRs + vmcnt coupling.
// v5: global_load_lds width=16 direct staging (fragment-order LDS == the
// required wave-uniform-base+lane*16 layout); ALL loads issue at step top
// (full-step flight window -> barrier drain is free); scalar sets ping-pong
// by step parity (no rotation movs); s_setprio(1) around MFMA clusters (T5).
#define FLASH_STEP(STEPN, RBASE, WDST, BQU, TAU, TBU, BQL, TAL, TBL)               \
    do {                                                                           \
        const int s1_ = ((STEPN) + 1 < 32) ? (STEPN) + 1 : 31;                     \
        const uint4* gsrc_ = gw + (size_t)s1_ * 1024;                              \
        gload_lds16(gsrc_, (WDST));                                                \
        gload_lds16(gsrc_ + 512, (WDST) + 8192);                                   \
        BQL = *(const uint4*)(bp + s1_ * 4);                                       \
        _Pragma("unroll")                                                          \
        for (int j_ = 0; j_ < 4; j_++) {                                           \
            TAL[j_] = *(const float4*)(tpp + (s1_ * 4 + j_) * 32);                 \
            TBL[j_] = *(const float4*)(tpp + (s1_ * 4 + j_) * 32 + 4);             \
        }                                                                          \
        const unsigned bqa_[4] = {BQU.x, BQU.y, BQU.z, BQU.w};                     \
        _Pragma("unroll")                                                          \
        for (int jtl_ = 0; jtl_ < 4; jtl_++) {                                     \
            const unsigned bits_ = (bqa_[jtl_] >> (kq * 8)) & 0xffu;               \
            const float tv_[8] = {TAU[jtl_].x, TAU[jtl_].y, TAU[jtl_].z,           \
                                  TAU[jtl_].w, TBU[jtl_].x, TBU[jtl_].y,           \
                                  TBU[jtl_].z, TBU[jtl_].w};                       \
            float p_[8];                                                           \
            _Pragma("unroll")                                                      \
            for (int r_ = 0; r_ < 8; r_++) {                                       \
                float e_ = s + tv_[r_];                                            \
                e_ = fmaxf(e_, 0.01f * e_);                                        \
                float pv_ = __builtin_amdgcn_exp2f(e_);                            \
                pv_ *= (float)((bits_ >> r_) & 1u);                                \
                p_[r_] = pv_;                                                      \
            }                                                                      \
            union { uint4 u; short8 s8; } pk_;                                     \
            pk_.u.x = cvtpk_bf16(p_[0], p_[1]);                                    \
            pk_.u.y = cvtpk_bf16(p_[2], p_[3]);                                    \
            pk_.u.z = cvtpk_bf16(p_[4], p_[5]);                                    \
            pk_.u.w = cvtpk_bf16(p_[6], p_[7]);                                    \
            const char* cb_ = (RBASE) + jtl_ * 4096 + lane * 16;                   \
            short8 v0_ = *(const short8*)(cb_);                                    \
            short8 v1_ = *(const short8*)(cb_ + 1024);                             \
            short8 v2_ = *(const short8*)(cb_ + 2048);                             \
            short8 v3_ = *(const short8*)(cb_ + 3072);                             \
            __builtin_amdgcn_s_setprio(1);                                         \
            acc0 = __builtin_amdgcn_mfma_f32_16x16x32_bf16(pk_.s8, v0_, acc0, 0, 0, 0); \
            acc1 = __builtin_amdgcn_mfma_f32_16x16x32_bf16(pk_.s8, v1_, acc1, 0, 0, 0); \
            acc2 = __builtin_amdgcn_mfma_f32_16x16x32_bf16(pk_.s8, v2_, acc2, 0, 0, 0); \
            acc3 = __builtin_amdgcn_mfma_f32_16x16x32_bf16(pk_.s8, v3_, acc3, 0, 0, 0); \
            asum = __builtin_amdgcn_mfma_f32_16x16x32_bf16(pk_.s8, ONES, asum, 0, 0, 0); \
            __builtin_amdgcn_s_setprio(0);                                         \
        }                                                                          \
        __syncthreads();                                                           \
    } while (0)

__global__ __launch_bounds__(512) void k_flash(const unsigned* __restrict__ bm32,
                                               const float* __restrict__ srcT,
                                               const float* __restrict__ trgT,
                                               const unsigned short* __restrict__ d1t,
                                               float* __restrict__ out) {
    __shared__ char vt[2][16384];           // 2 x (4 jt x 4 dt x 64 lanes x 16B)

    const int t = threadIdx.x;              // 0..511
    const int lane = t & 63;
    const int w = t >> 6;                   // 0..7
    const int col = lane & 15;
    const int kq = lane >> 4;
    const int i0 = blockIdx.x * 128;
    const int h = blockIdx.y;
    const int m = i0 + w * 16 + col;        // this lane's P row

    const float s = srcT[(size_t)h * NN + m];
    const unsigned* bp = bm32 + (size_t)m * 128;
    const float* tpp = trgT + (size_t)h * NN + kq * 8;
    const uint4* gv = (const uint4*)d1t + (size_t)h * 32768;  // 128jt x 256 chunks
    const uint4* gw = gv + w * 64 + lane;   // per-lane staging source base
    char* l0 = vt[0] + w * 1024;            // wave-uniform LDS dest bases
    char* l1 = vt[1] + w * 1024;
    const short8 ONES = {0x3F80, 0x3F80, 0x3F80, 0x3F80, 0x3F80, 0x3F80, 0x3F80, 0x3F80};

    f32x4 acc0 = {0.f, 0.f, 0.f, 0.f}, acc1 = acc0, acc2 = acc0, acc3 = acc0;
    f32x4 asum = acc0;

    uint4 bqA, bqB;
    float4 tAA[4], tBA[4], tAB[4], tBB[4];

    // ---- prologue: tile0 -> LDS buf0 (direct); tile0 scalars -> A-set ----
    gload_lds16(gw, l0);
    gload_lds16(gw + 512, l0 + 8192);
    bqA = *(const uint4*)(bp);
#pragma unroll
    for (int j = 0; j < 4; j++) {
        tAA[j] = *(const float4*)(tpp + j * 32);
        tBA[j] = *(const float4*)(tpp + j * 32 + 4);
    }
    __syncthreads();

    for (int it = 0; it < 16; it++) {
        FLASH_STEP(2 * it,     vt[0], l1, bqA, tAA, tBA, bqB, tAB, tBB);
        FLASH_STEP(2 * it + 1, vt[1], l0, bqB, tAB, tBB, bqA, tAA, tBA);
    }

    // ---- normalize + store: lane (kq,col) has den(row kq*4+r) in asum[r] ----
    f32x4 accs[4] = {acc0, acc1, acc2, acc3};
#pragma unroll
    for (int r = 0; r < 4; r++) {
        const int row = i0 + w * 16 + kq * 4 + r;
        const float dv = asum[r];
        const float inv = (dv > 0.f) ? (1.f / dv) : 0.f;
        float* op = out + (size_t)row * HD + h * 64;
#pragma unroll
        for (int dt = 0; dt < 4; dt++)
            op[dt * 16 + col] = accs[dt][r] * inv;
    }
}

extern "C" void kernel_launch(void* const* d_in, const int* in_sizes, int n_in,
                              void* d_out, int out_size, void* d_ws, size_t ws_size,
                              hipStream_t stream) {
    const float* data = (const float*)d_in[0];   // (4096, 512)
    const float* conn = (const float*)d_in[1];   // (4096, 4096)
    const float* W    = (const float*)d_in[2];   // (512, 512)
    const float* bias = (const float*)d_in[3];   // (512,)
    const float* sp   = (const float*)d_in[4];   // (1, 8, 64)
    const float* tp   = (const float*)d_in[5];   // (1, 8, 64)
    float* out = (float*)d_out;                  // (4096, 512) fp32

    unsigned short* d1t = (unsigned short*)d_ws;              // 4 MB, fragment order
    unsigned short* Ab  = d1t + (size_t)HD * NN;              // 4 MB
    unsigned short* Wb  = Ab + (size_t)NN * IN_DIM;           // 512 KB
    float* srcT = (float*)(Wb + (size_t)HD * IN_DIM);         // 128 KB
    float* trgT = srcT + NH * NN;                             // 128 KB
    unsigned long long* bm = (unsigned long long*)(trgT + NH * NN); // 2 MB
    // total ~10.75 MB

    const int n4A = NN * IN_DIM / 4;   // 524288
    const int n4B = HD * IN_DIM / 4;   // 65536
    k_cast_scan<<<dim3(CAST_WGS + SCAN_WGS), 256, 0, stream>>>(data, Ab, n4A, W, Wb, n4B,
                                                               conn, bm);
    k_gemm_fused<<<dim3(NH, NN / 64), 512, 0, stream>>>(Ab, Wb, bias, sp, tp,
                                                        d1t, srcT, trgT);
    k_flash<<<dim3(NN / 128, NH), 512, 0, stream>>>((const unsigned*)bm, srcT, trgT, d1t, out);
}